// Round 1
// baseline (248.829 us; speedup 1.0000x reference)
//
#include <hip/hip_runtime.h>
#include <stdint.h>

#define MM 16384
#define KK 2048
#define NN 2048
#define GG 64
#define EPSV 1e-5f

typedef short short8 __attribute__((ext_vector_type(8)));
typedef float floatx4 __attribute__((ext_vector_type(4)));

__device__ __forceinline__ uint16_t f2bf(float f) {
  uint32_t u = __float_as_uint(f);
  u = (u + 0x7fffu + ((u >> 16) & 1u)) >> 16;
  return (uint16_t)u;
}

__global__ void cvt_f32_to_bf16(const float* __restrict__ src,
                                uint16_t* __restrict__ dst, int n4) {
  int stride = gridDim.x * blockDim.x;
  for (int i = blockIdx.x * blockDim.x + threadIdx.x; i < n4; i += stride) {
    float4 v = reinterpret_cast<const float4*>(src)[i];
    ushort4 o;
    o.x = f2bf(v.x); o.y = f2bf(v.y); o.z = f2bf(v.z); o.w = f2bf(v.w);
    reinterpret_cast<ushort4*>(dst)[i] = o;
  }
}

__device__ __forceinline__ void gload_lds16(const void* g, void* l) {
  __builtin_amdgcn_global_load_lds(
      (const __attribute__((address_space(1))) void*)g,
      (__attribute__((address_space(3))) void*)l, 16, 0, 0);
}

#define BM 128
#define BN 128
#define BK 64

// 128x128 tile, 4 waves (2x2), each wave 64x64 = 4x4 frags of 16x16x32 MFMA.
// LDS tiles [128 rows][64 k] bf16 with byte-XOR swizzle ((row&7)<<4) applied on
// the READ side; global_load_lds writes linearly so the SOURCE address carries
// the inverse (same involution) swizzle.  (Guide T2 + rule #21.)
__global__ __launch_bounds__(256)
void gemm_gn_silu(const uint16_t* __restrict__ xb,  // M x K bf16
                  const uint16_t* __restrict__ wb,  // N x K bf16
                  const float* __restrict__ bias,   // N
                  const float* __restrict__ gnw,    // G
                  const float* __restrict__ gnb,    // G
                  const float* __restrict__ mw,     // N
                  float* __restrict__ out) {        // M x N f32
  __shared__ __align__(16) char As[BM * BK * 2];
  __shared__ __align__(16) char Bs[BM * BK * 2];

  int bid = blockIdx.x;
  // XCD chunk swizzle: 2048 blocks, 8 XCDs, 256 consecutive tiles per XCD.
  int wgs = ((bid & 7) << 8) | (bid >> 3);
  int tm = wgs >> 4;          // 0..127 row tile
  int tn = wgs & 15;          // 0..15  col tile
  int row0 = tm * BM;
  int col0 = tn * BN;

  int t = threadIdx.x;
  int lane = t & 63;
  int wid = t >> 6;
  int wm = wid >> 1, wn = wid & 1;   // 2x2 wave grid
  int llo = lane & 15, lhi = lane >> 4;

  const char* xg  = (const char*)xb + (size_t)row0 * (KK * 2);
  const char* wgp = (const char*)wb + (size_t)col0 * (KK * 2);

  // Staging: 16KB per tile, 256 threads x 16B -> 4 insts each for A and B.
  // LDS linear offset o -> (row=o>>7, pb=o&127); source k-byte = pb ^ ((row&7)<<4).
  int so[4];   // LDS byte offset
  int sg[4];   // global byte offset within tile row-slab (row*rowstride + swz k)
  #pragma unroll
  for (int i = 0; i < 4; ++i) {
    int o = i * 4096 + t * 16;
    so[i] = o;
    int r = o >> 7;
    int pb = o & 127;
    sg[i] = r * (KK * 2) + (pb ^ ((r & 7) << 4));
  }

  floatx4 acc[4][4] = {};

  for (int kt = 0; kt < KK / BK; ++kt) {
    int kb0 = kt * (BK * 2);
    #pragma unroll
    for (int i = 0; i < 4; ++i) {
      gload_lds16(xg  + sg[i] + kb0, As + so[i]);
      gload_lds16(wgp + sg[i] + kb0, Bs + so[i]);
    }
    __syncthreads();   // compiler drains vmcnt before s_barrier
    #pragma unroll
    for (int kk2 = 0; kk2 < 2; ++kk2) {
      int ca = kk2 * 64 + (lane & 48);   // byte col: (lane>>4)*16
      short8 a[4], b[4];
      #pragma unroll
      for (int f = 0; f < 4; ++f) {
        int ra  = wm * 64 + f * 16 + llo;
        a[f] = *(const short8*)(As + ra * 128 + (ca ^ ((ra & 7) << 4)));
        int rbb = wn * 64 + f * 16 + llo;
        b[f] = *(const short8*)(Bs + rbb * 128 + (ca ^ ((rbb & 7) << 4)));
      }
      #pragma unroll
      for (int mi = 0; mi < 4; ++mi)
        #pragma unroll
        for (int ni = 0; ni < 4; ++ni)
          acc[mi][ni] = __builtin_amdgcn_mfma_f32_16x16x32_bf16(
              a[mi], b[ni], acc[mi][ni], 0, 0, 0);
    }
    __syncthreads();
  }

  // ---- fused epilogue: bias + GroupNorm(32) + SiLU * mw * SiLU ----
  // C/D frag: col = cb + ni*16 + llo ; row = rb + mi*16 + lhi*4 + j  (m89 layout)
  int cb = col0 + wn * 64;   // wave col base: exactly 2 groups of 32
  int rb = row0 + wm * 64;

  float bias_v[4], mw_v[4];
  #pragma unroll
  for (int ni = 0; ni < 4; ++ni) {
    int c = cb + ni * 16 + llo;
    bias_v[ni] = bias[c];
    mw_v[ni] = mw[c];
  }
  #pragma unroll
  for (int mi = 0; mi < 4; ++mi)
    #pragma unroll
    for (int ni = 0; ni < 4; ++ni)
      #pragma unroll
      for (int j = 0; j < 4; ++j)
        acc[mi][ni][j] += bias_v[ni];

  #pragma unroll
  for (int mi = 0; mi < 4; ++mi) {
    #pragma unroll
    for (int gp = 0; gp < 2; ++gp) {        // group = frag pair {2gp, 2gp+1}
      int g = (cb >> 5) + gp;
      float gw = gnw[g], gb = gnb[g];
      float s[4], ss[4];
      #pragma unroll
      for (int j = 0; j < 4; ++j) {
        float a0 = acc[mi][2 * gp][j];
        float a1 = acc[mi][2 * gp + 1][j];
        s[j]  = a0 + a1;
        ss[j] = a0 * a0 + a1 * a1;
      }
      // reduce across the 16 lanes sharing lhi (masks 1,2,4,8 stay in-group)
      #pragma unroll
      for (int off = 1; off < 16; off <<= 1) {
        #pragma unroll
        for (int j = 0; j < 4; ++j) {
          s[j]  += __shfl_xor(s[j],  off, 64);
          ss[j] += __shfl_xor(ss[j], off, 64);
        }
      }
      #pragma unroll
      for (int j = 0; j < 4; ++j) {
        float mean = s[j] * (1.0f / 32.0f);
        float var  = ss[j] * (1.0f / 32.0f) - mean * mean;
        float rstd = rsqrtf(var + EPSV);
        int r = rb + mi * 16 + lhi * 4 + j;
        #pragma unroll
        for (int nn = 0; nn < 2; ++nn) {
          int ni = 2 * gp + nn;
          float v = (acc[mi][ni][j] - mean) * rstd * gw + gb;
          v = v / (1.0f + __expf(-v));   // SiLU
          v = v * mw_v[ni];
          v = v / (1.0f + __expf(-v));   // SiLU
          out[(size_t)r * NN + (cb + ni * 16 + llo)] = v;
        }
      }
    }
  }
}

// ---------------- naive f32 fallback (only if ws too small) ----------------
__global__ void naive_gemm(const float* __restrict__ x, const float* __restrict__ w,
                           const float* __restrict__ bias, float* __restrict__ out) {
  size_t idx = (size_t)blockIdx.x * 256 + threadIdx.x;
  int m = (int)(idx >> 11);
  int n = (int)(idx & 2047);
  const float* xr = x + (size_t)m * KK;
  const float* wr = w + (size_t)n * KK;
  float s = bias[n];
  for (int k = 0; k < KK; k += 4)
    s += xr[k] * wr[k] + xr[k+1] * wr[k+1] + xr[k+2] * wr[k+2] + xr[k+3] * wr[k+3];
  out[idx] = s;
}

__global__ void naive_post(float* __restrict__ out, const float* __restrict__ gnw,
                           const float* __restrict__ gnb, const float* __restrict__ mw) {
  size_t idx = (size_t)blockIdx.x * 256 + threadIdx.x;  // M*G
  int m = (int)(idx >> 6);
  int g = (int)(idx & 63);
  float* p = out + (size_t)m * NN + g * 32;
  float s = 0.f, ss = 0.f;
  for (int j = 0; j < 32; ++j) { float v = p[j]; s += v; ss += v * v; }
  float mean = s * (1.0f / 32.0f);
  float var  = ss * (1.0f / 32.0f) - mean * mean;
  float rstd = rsqrtf(var + EPSV);
  float gw = gnw[g], gb = gnb[g];
  for (int j = 0; j < 32; ++j) {
    float v = (p[j] - mean) * rstd * gw + gb;
    v = v / (1.0f + __expf(-v));
    v = v * mw[g * 32 + j];
    v = v / (1.0f + __expf(-v));
    p[j] = v;
  }
}

extern "C" void kernel_launch(void* const* d_in, const int* in_sizes, int n_in,
                              void* d_out, int out_size, void* d_ws, size_t ws_size,
                              hipStream_t stream) {
  const float* x    = (const float*)d_in[0];
  const float* wgt  = (const float*)d_in[1];
  const float* bias = (const float*)d_in[2];
  const float* gnw  = (const float*)d_in[3];
  const float* gnb  = (const float*)d_in[4];
  const float* mwp  = (const float*)d_in[5];
  float* out = (float*)d_out;

  size_t need = ((size_t)MM * KK + (size_t)NN * KK) * 2;
  if (ws_size >= need) {
    uint16_t* xbf = (uint16_t*)d_ws;
    uint16_t* wbf = xbf + (size_t)MM * KK;
    cvt_f32_to_bf16<<<2048, 256, 0, stream>>>(x, xbf, (MM * KK) / 4);
    cvt_f32_to_bf16<<<512, 256, 0, stream>>>(wgt, wbf, (NN * KK) / 4);
    gemm_gn_silu<<<2048, 256, 0, stream>>>(xbf, wbf, bias, gnw, gnb, mwp, out);
  } else {
    naive_gemm<<<(MM * (size_t)NN) / 256, 256, 0, stream>>>(x, wgt, bias, out);
    naive_post<<<(MM * GG) / 256, 256, 0, stream>>>(out, gnw, gnb, mwp);
  }
}

// Round 2
// 213.741 us; speedup vs baseline: 1.1642x; 1.1642x over previous
//
#include <hip/hip_runtime.h>
#include <stdint.h>

#define MM 16384
#define KK 2048
#define NN 2048
#define GG 64
#define EPSV 1e-5f
#define NT 32           // K tiles of 64
#define NITER 16        // NT/2

typedef short short8 __attribute__((ext_vector_type(8)));
typedef float floatx4 __attribute__((ext_vector_type(4)));

__device__ __forceinline__ uint16_t f2bf(float f) {
  uint32_t u = __float_as_uint(f);
  u = (u + 0x7fffu + ((u >> 16) & 1u)) >> 16;
  return (uint16_t)u;
}

__global__ void cvt_f32_to_bf16(const float* __restrict__ src,
                                uint16_t* __restrict__ dst, int n4) {
  int stride = gridDim.x * blockDim.x;
  for (int i = blockIdx.x * blockDim.x + threadIdx.x; i < n4; i += stride) {
    float4 v = reinterpret_cast<const float4*>(src)[i];
    ushort4 o;
    o.x = f2bf(v.x); o.y = f2bf(v.y); o.z = f2bf(v.z); o.w = f2bf(v.w);
    reinterpret_cast<ushort4*>(dst)[i] = o;
  }
}

__device__ __forceinline__ void gload_lds16(const void* g, void* l) {
  __builtin_amdgcn_global_load_lds(
      (const __attribute__((address_space(1))) void*)g,
      (__attribute__((address_space(3))) void*)l, 16, 0, 0);
}

#define BAR() __asm__ volatile("s_barrier" ::: "memory")
#define VMC4() __asm__ volatile("s_waitcnt vmcnt(4)" ::: "memory")
#define VMC0() __asm__ volatile("s_waitcnt vmcnt(0)" ::: "memory")

// 256x256 tile, BK=64, 8 waves (2Mx4N), 8-phase schedule with counted vmcnt.
// LDS 128KB: buf b at b*65536: A[256r][64k] bf16 (+0), B[256c][64k] (+32768).
// T2 XOR swizzle ((row&7)<<4 on byte col) applied on read; global source
// pre-swizzled, LDS dest linear (rule #21). Fused bias+GN(32)+SiLU*mw*SiLU.
__global__ __launch_bounds__(512, 2)
void gemm_gn_silu_8p(const uint16_t* __restrict__ xb,  // M x K bf16
                     const uint16_t* __restrict__ wb,  // N x K bf16
                     const float* __restrict__ bias,   // N
                     const float* __restrict__ gnw,    // G
                     const float* __restrict__ gnb,    // G
                     const float* __restrict__ mw,     // N
                     float* __restrict__ out) {        // M x N f32
  extern __shared__ char lds[];   // 131072 bytes

  int bid = blockIdx.x;
  // XCD chunk swizzle: 512 blocks, 8 XCDs, 64 consecutive tiles per XCD.
  int wgs = ((bid & 7) << 6) | (bid >> 3);
  int tm = wgs >> 3;          // 0..63  (M tiles)
  int tn = wgs & 7;           // 0..7   (N tiles)
  int row0 = tm * 256;
  int col0 = tn * 256;

  int t = threadIdx.x;
  int lane = t & 63;
  int wid = t >> 6;
  int wm = wid >> 2, wn = wid & 3;   // 2x4 wave grid
  int llo = lane & 15, lhi = lane >> 4;
  int sw = (llo & 7) << 4;

  const char* xgb = (const char*)xb + (size_t)row0 * (KK * 2);
  const char* wgb = (const char*)wb + (size_t)col0 * (KK * 2);

  // staging addresses: thread t covers half-tile bytes [t*16, t*16+16) and
  // [t*16+8192, ...). LDS dest linear; source column pre-swizzled.
  int o16 = t * 16;                 // 0..8176
  int srow = o16 >> 7;              // 0..63
  int spb = (o16 & 127) ^ ((srow & 7) << 4);
  const char* gaSrc = xgb + (size_t)srow * (KK * 2) + spb;
  const char* gbSrc = wgb + (size_t)srow * (KK * 2) + spb;

  auto stageA = [&](int buf, int h, int kt) {
    if (kt < NT) {
      const char* s = gaSrc + (size_t)h * (128 * KK * 2) + (size_t)kt * 128;
      char* d = lds + buf * 65536 + h * 16384 + o16;
      gload_lds16(s, d);
      gload_lds16(s + 64 * (KK * 2), d + 8192);
    }
  };
  auto stageB = [&](int buf, int h, int kt) {
    if (kt < NT) {
      const char* s = gbSrc + (size_t)h * (128 * KK * 2) + (size_t)kt * 128;
      char* d = lds + buf * 65536 + 32768 + h * 16384 + o16;
      gload_lds16(s, d);
      gload_lds16(s + 64 * (KK * 2), d + 8192);
    }
  };

  short8 a[4][2], blo[2][2], bhi[2][2];
  auto rdA = [&](int buf, int mh) {
    #pragma unroll
    for (int mi2 = 0; mi2 < 4; ++mi2) {
      int r = wm * 128 + mh * 64 + mi2 * 16 + llo;
      const char* base = lds + buf * 65536 + r * 128;
      #pragma unroll
      for (int kk = 0; kk < 2; ++kk)
        a[mi2][kk] = *(const short8*)(base + ((kk * 64 + lhi * 16) ^ sw));
    }
  };
  auto rdB = [&](int buf, int nh, short8 bq[2][2]) {
    #pragma unroll
    for (int ni2 = 0; ni2 < 2; ++ni2) {
      int c = wn * 64 + nh * 32 + ni2 * 16 + llo;
      const char* base = lds + buf * 65536 + 32768 + c * 128;
      #pragma unroll
      for (int kk = 0; kk < 2; ++kk)
        bq[ni2][kk] = *(const short8*)(base + ((kk * 64 + lhi * 16) ^ sw));
    }
  };

  floatx4 acc[8][4] = {};
  auto mfmaQ = [&](int mh, int nh, short8 bq[2][2]) {
    __builtin_amdgcn_s_setprio(1);
    #pragma unroll
    for (int mi2 = 0; mi2 < 4; ++mi2)
      #pragma unroll
      for (int ni2 = 0; ni2 < 2; ++ni2)
        #pragma unroll
        for (int kk = 0; kk < 2; ++kk)
          acc[mh * 4 + mi2][nh * 2 + ni2] =
              __builtin_amdgcn_mfma_f32_16x16x32_bf16(
                  a[mi2][kk], bq[ni2][kk], acc[mh * 4 + mi2][nh * 2 + ni2],
                  0, 0, 0);
    __builtin_amdgcn_s_setprio(0);
  };

  // Prologue: tile0 (B,A all halves) + tile1 B halves = 12 loads.
  stageB(0, 0, 0); stageB(0, 1, 0);
  stageA(0, 0, 0); stageA(0, 1, 0);
  stageB(1, 0, 1); stageB(1, 1, 1);
  VMC4();   // tile0's 8 loads landed; tile1 B (4) may stay in flight
  BAR();

  #pragma unroll 1
  for (int i = 0; i < NITER; ++i) {
    int t1 = 2 * i + 1, t2 = 2 * i + 2, t3 = 2 * i + 3;
    // ---- K-tile 2i in buf0 ----
    // p1: quadrant (mh0, nh0)
    rdA(0, 0); rdB(0, 0, blo);
    stageA(1, 0, t1);
    BAR(); mfmaQ(0, 0, blo); BAR();
    // p2: (mh0, nh1)
    rdB(0, 1, bhi);
    stageA(1, 1, t1);
    BAR(); mfmaQ(0, 1, bhi); BAR();
    // p3: (mh1, nh1)
    rdA(0, 1);
    stageB(0, 0, t2);
    BAR(); mfmaQ(1, 1, bhi); BAR();
    // p4: (mh1, nh0)
    stageB(0, 1, t2);
    BAR(); mfmaQ(1, 0, blo);
    if (i == NITER - 1) { VMC0(); } else { VMC4(); }
    BAR();
    // ---- K-tile 2i+1 in buf1 ----
    // p5
    rdA(1, 0); rdB(1, 0, blo);
    stageA(0, 0, t2);
    BAR(); mfmaQ(0, 0, blo); BAR();
    // p6
    rdB(1, 1, bhi);
    stageA(0, 1, t2);
    BAR(); mfmaQ(0, 1, bhi); BAR();
    // p7
    rdA(1, 1);
    stageB(1, 0, t3);
    BAR(); mfmaQ(1, 1, bhi); BAR();
    // p8
    stageB(1, 1, t3);
    BAR(); mfmaQ(1, 0, blo);
    if (i < NITER - 1) { VMC4(); }
    BAR();
  }

  // ---- fused epilogue: bias + GroupNorm(32) + SiLU * mw * SiLU ----
  // C/D frag: col = cb + ni*16 + llo ; row = rb + mi*16 + lhi*4 + j
  int cb = col0 + wn * 64;   // 2 groups of 32 per wave
  int rb = row0 + wm * 128;

  float bias_v[4], mw_v[4];
  #pragma unroll
  for (int ni = 0; ni < 4; ++ni) {
    int c = cb + ni * 16 + llo;
    bias_v[ni] = bias[c];
    mw_v[ni] = mw[c];
  }
  #pragma unroll
  for (int mi = 0; mi < 8; ++mi)
    #pragma unroll
    for (int ni = 0; ni < 4; ++ni)
      #pragma unroll
      for (int j = 0; j < 4; ++j)
        acc[mi][ni][j] += bias_v[ni];

  #pragma unroll
  for (int mi = 0; mi < 8; ++mi) {
    #pragma unroll
    for (int gp = 0; gp < 2; ++gp) {
      int g = (cb >> 5) + gp;
      float gw = gnw[g], gb = gnb[g];
      float s[4], ss[4];
      #pragma unroll
      for (int j = 0; j < 4; ++j) {
        float a0 = acc[mi][2 * gp][j];
        float a1 = acc[mi][2 * gp + 1][j];
        s[j] = a0 + a1;
        ss[j] = a0 * a0 + a1 * a1;
      }
      #pragma unroll
      for (int off = 1; off < 16; off <<= 1) {
        #pragma unroll
        for (int j = 0; j < 4; ++j) {
          s[j]  += __shfl_xor(s[j],  off, 64);
          ss[j] += __shfl_xor(ss[j], off, 64);
        }
      }
      #pragma unroll
      for (int j = 0; j < 4; ++j) {
        float mean = s[j] * (1.0f / 32.0f);
        float var  = ss[j] * (1.0f / 32.0f) - mean * mean;
        float rstd = rsqrtf(var + EPSV);
        int r = rb + mi * 16 + lhi * 4 + j;
        #pragma unroll
        for (int nn = 0; nn < 2; ++nn) {
          int ni = 2 * gp + nn;
          float v = (acc[mi][ni][j] - mean) * rstd * gw + gb;
          v = v / (1.0f + __expf(-v));   // SiLU
          v = v * mw_v[ni];
          v = v / (1.0f + __expf(-v));   // SiLU
          out[(size_t)r * NN + (cb + ni * 16 + llo)] = v;
        }
      }
    }
  }
}

// ---------------- naive f32 fallback (only if ws too small) ----------------
__global__ void naive_gemm(const float* __restrict__ x, const float* __restrict__ w,
                           const float* __restrict__ bias, float* __restrict__ out) {
  size_t idx = (size_t)blockIdx.x * 256 + threadIdx.x;
  int m = (int)(idx >> 11);
  int n = (int)(idx & 2047);
  const float* xr = x + (size_t)m * KK;
  const float* wr = w + (size_t)n * KK;
  float s = bias[n];
  for (int k = 0; k < KK; k += 4)
    s += xr[k] * wr[k] + xr[k+1] * wr[k+1] + xr[k+2] * wr[k+2] + xr[k+3] * wr[k+3];
  out[idx] = s;
}

__global__ void naive_post(float* __restrict__ out, const float* __restrict__ gnw,
                           const float* __restrict__ gnb, const float* __restrict__ mw) {
  size_t idx = (size_t)blockIdx.x * 256 + threadIdx.x;  // M*G
  int m = (int)(idx >> 6);
  int g = (int)(idx & 63);
  float* p = out + (size_t)m * NN + g * 32;
  float s = 0.f, ss = 0.f;
  for (int j = 0; j < 32; ++j) { float v = p[j]; s += v; ss += v * v; }
  float mean = s * (1.0f / 32.0f);
  float var  = ss * (1.0f / 32.0f) - mean * mean;
  float rstd = rsqrtf(var + EPSV);
  float gw = gnw[g], gb = gnb[g];
  for (int j = 0; j < 32; ++j) {
    float v = (p[j] - mean) * rstd * gw + gb;
    v = v / (1.0f + __expf(-v));
    v = v * mw[g * 32 + j];
    v = v / (1.0f + __expf(-v));
    p[j] = v;
  }
}

extern "C" void kernel_launch(void* const* d_in, const int* in_sizes, int n_in,
                              void* d_out, int out_size, void* d_ws, size_t ws_size,
                              hipStream_t stream) {
  const float* x    = (const float*)d_in[0];
  const float* wgt  = (const float*)d_in[1];
  const float* bias = (const float*)d_in[2];
  const float* gnw  = (const float*)d_in[3];
  const float* gnb  = (const float*)d_in[4];
  const float* mwp  = (const float*)d_in[5];
  float* out = (float*)d_out;

  size_t need = ((size_t)MM * KK + (size_t)NN * KK) * 2;
  if (ws_size >= need) {
    uint16_t* xbf = (uint16_t*)d_ws;
    uint16_t* wbf = xbf + (size_t)MM * KK;
    cvt_f32_to_bf16<<<2048, 256, 0, stream>>>(x, xbf, (MM * KK) / 4);
    cvt_f32_to_bf16<<<512, 256, 0, stream>>>(wgt, wbf, (NN * KK) / 4);
    (void)hipFuncSetAttribute((const void*)gemm_gn_silu_8p,
                              hipFuncAttributeMaxDynamicSharedMemorySize, 131072);
    gemm_gn_silu_8p<<<512, 512, 131072, stream>>>(xbf, wbf, bias, gnw, gnb, mwp, out);
  } else {
    naive_gemm<<<(MM * (size_t)NN) / 256, 256, 0, stream>>>(x, wgt, bias, out);
    naive_post<<<(MM * GG) / 256, 256, 0, stream>>>(out, gnw, gnb, mwp);
  }
}

// Round 3
// 212.514 us; speedup vs baseline: 1.1709x; 1.0058x over previous
//
#include <hip/hip_runtime.h>
#include <stdint.h>

#define MM 16384
#define KK 2048
#define NN 2048
#define GG 64
#define EPSV 1e-5f
#define NT 32           // K tiles of 64
#define NITER 16        // NT/2

typedef short short8 __attribute__((ext_vector_type(8)));
typedef float floatx4 __attribute__((ext_vector_type(4)));

__device__ __forceinline__ uint16_t f2bf(float f) {
  uint32_t u = __float_as_uint(f);
  u = (u + 0x7fffu + ((u >> 16) & 1u)) >> 16;
  return (uint16_t)u;
}

__global__ void cvt_f32_to_bf16(const float* __restrict__ src,
                                uint16_t* __restrict__ dst, int n4) {
  int stride = gridDim.x * blockDim.x;
  for (int i = blockIdx.x * blockDim.x + threadIdx.x; i < n4; i += stride) {
    float4 v = reinterpret_cast<const float4*>(src)[i];
    ushort4 o;
    o.x = f2bf(v.x); o.y = f2bf(v.y); o.z = f2bf(v.z); o.w = f2bf(v.w);
    reinterpret_cast<ushort4*>(dst)[i] = o;
  }
}

__device__ __forceinline__ void gload_lds16(const void* g, void* l) {
  __builtin_amdgcn_global_load_lds(
      (const __attribute__((address_space(1))) void*)g,
      (__attribute__((address_space(3))) void*)l, 16, 0, 0);
}

#define BAR() __asm__ volatile("s_barrier" ::: "memory")
#define VMC4() __asm__ volatile("s_waitcnt vmcnt(4)" ::: "memory")
#define VMC0() __asm__ volatile("s_waitcnt vmcnt(0)" ::: "memory")

// 256x256 tile, BK=64, 8 waves (2Mx4N), 8-phase schedule with counted vmcnt.
// LDS 128KB: buf b at b*65536: A[256r][64k] bf16 (+0), B[256c][64k] (+32768).
// T2 XOR swizzle ((row&7)<<4 on byte col) applied on read; global source
// pre-swizzled, LDS dest linear (rule #21). Fused bias+GN(32)+SiLU*mw*SiLU.
// r3: kk-OUTER MFMA order (8 independent MFMAs between same-acc reuse) +
//     precomputed 32-bit LDS read offsets (ds_read offset:imm, no per-phase
//     address VALU).
__global__ __launch_bounds__(512, 2)
void gemm_gn_silu_8p(const uint16_t* __restrict__ xb,  // M x K bf16
                     const uint16_t* __restrict__ wb,  // N x K bf16
                     const float* __restrict__ bias,   // N
                     const float* __restrict__ gnw,    // G
                     const float* __restrict__ gnb,    // G
                     const float* __restrict__ mw,     // N
                     float* __restrict__ out) {        // M x N f32
  extern __shared__ char lds[];   // 131072 bytes

  int bid = blockIdx.x;
  // XCD chunk swizzle: 512 blocks, 8 XCDs, 64 consecutive tiles per XCD.
  int wgs = ((bid & 7) << 6) | (bid >> 3);
  int tm = wgs >> 3;          // 0..63  (M tiles)
  int tn = wgs & 7;           // 0..7   (N tiles)
  int row0 = tm * 256;
  int col0 = tn * 256;

  int t = threadIdx.x;
  int lane = t & 63;
  int wid = t >> 6;
  int wm = wid >> 2, wn = wid & 3;   // 2x4 wave grid
  int llo = lane & 15, lhi = lane >> 4;
  int sw = (llo & 7) << 4;

  const char* xgb = (const char*)xb + (size_t)row0 * (KK * 2);
  const char* wgb = (const char*)wb + (size_t)col0 * (KK * 2);

  // staging addresses: thread t covers half-tile bytes [t*16, t*16+16) and
  // [t*16+8192, ...). LDS dest linear; source column pre-swizzled.
  int o16 = t * 16;                 // 0..8176
  int srow = o16 >> 7;              // 0..63
  int spb = (o16 & 127) ^ ((srow & 7) << 4);
  const char* gaSrc = xgb + (size_t)srow * (KK * 2) + spb;
  const char* gbSrc = wgb + (size_t)srow * (KK * 2) + spb;

  auto stageA = [&](int buf, int h, int kt) {
    if (kt < NT) {
      const char* s = gaSrc + (size_t)h * (128 * KK * 2) + (size_t)kt * 128;
      char* d = lds + buf * 65536 + h * 16384 + o16;
      gload_lds16(s, d);
      gload_lds16(s + 64 * (KK * 2), d + 8192);
    }
  };
  auto stageB = [&](int buf, int h, int kt) {
    if (kt < NT) {
      const char* s = gbSrc + (size_t)h * (128 * KK * 2) + (size_t)kt * 128;
      char* d = lds + buf * 65536 + 32768 + h * 16384 + o16;
      gload_lds16(s, d);
      gload_lds16(s + 64 * (KK * 2), d + 8192);
    }
  };

  // Precomputed LDS byte offsets for fragment reads: [buf][kk].
  // row = (wm*128 + llo) + mh*64 + mi2*16; (row&7)==llo&7 for all frags, so
  // the swizzled k-offset ((kk*64 + lhi*16)^sw) is fragment-invariant and the
  // fragment selector (mh*8192 + mi2*2048) is a compile-time immediate.
  uint32_t aOff[2][2], bOff[2][2];
  #pragma unroll
  for (int buf = 0; buf < 2; ++buf)
    #pragma unroll
    for (int kk = 0; kk < 2; ++kk) {
      uint32_t ko = (uint32_t)((kk * 64 + lhi * 16) ^ sw);
      aOff[buf][kk] = buf * 65536u + (uint32_t)(wm * 128 + llo) * 128u + ko;
      bOff[buf][kk] = buf * 65536u + 32768u + (uint32_t)(wn * 64 + llo) * 128u + ko;
    }

  short8 a[4][2], blo[2][2], bhi[2][2];

  floatx4 acc[8][4] = {};

#define RDA(buf, mh)                                                       \
  {                                                                        \
    _Pragma("unroll") for (int kk = 0; kk < 2; ++kk)                       \
        _Pragma("unroll") for (int mi2 = 0; mi2 < 4; ++mi2)                \
            a[mi2][kk] = *(const short8*)(lds + aOff[buf][kk] +            \
                                          (mh)*8192 + mi2 * 2048);         \
  }
#define RDB(buf, nh, bq)                                                   \
  {                                                                        \
    _Pragma("unroll") for (int kk = 0; kk < 2; ++kk)                       \
        _Pragma("unroll") for (int ni2 = 0; ni2 < 2; ++ni2)                \
            bq[ni2][kk] = *(const short8*)(lds + bOff[buf][kk] +           \
                                           (nh)*4096 + ni2 * 2048);        \
  }
  // kk OUTER: 8 independent MFMAs between accumulator reuse (dep distance 8).
#define MFMAQ(mh, nh, bq)                                                  \
  {                                                                        \
    __builtin_amdgcn_s_setprio(1);                                         \
    _Pragma("unroll") for (int kk = 0; kk < 2; ++kk)                       \
        _Pragma("unroll") for (int mi2 = 0; mi2 < 4; ++mi2)                \
            _Pragma("unroll") for (int ni2 = 0; ni2 < 2; ++ni2)            \
                acc[(mh)*4 + mi2][(nh)*2 + ni2] =                          \
                    __builtin_amdgcn_mfma_f32_16x16x32_bf16(               \
                        a[mi2][kk], bq[ni2][kk],                           \
                        acc[(mh)*4 + mi2][(nh)*2 + ni2], 0, 0, 0);         \
    __builtin_amdgcn_s_setprio(0);                                         \
  }

  // Prologue: tile0 (B,A all halves) + tile1 B halves = 12 loads.
  stageB(0, 0, 0); stageB(0, 1, 0);
  stageA(0, 0, 0); stageA(0, 1, 0);
  stageB(1, 0, 1); stageB(1, 1, 1);
  VMC4();   // tile0's 8 loads landed; tile1 B (4) may stay in flight
  BAR();

  #pragma unroll 1
  for (int i = 0; i < NITER; ++i) {
    int t1 = 2 * i + 1, t2 = 2 * i + 2, t3 = 2 * i + 3;
    // ---- K-tile 2i in buf0 ----
    // p1: quadrant (mh0, nh0)
    RDA(0, 0); RDB(0, 0, blo);
    stageA(1, 0, t1);
    BAR(); MFMAQ(0, 0, blo); BAR();
    // p2: (mh0, nh1)
    RDB(0, 1, bhi);
    stageA(1, 1, t1);
    BAR(); MFMAQ(0, 1, bhi); BAR();
    // p3: (mh1, nh1)
    RDA(0, 1);
    stageB(0, 0, t2);
    BAR(); MFMAQ(1, 1, bhi); BAR();
    // p4: (mh1, nh0)
    stageB(0, 1, t2);
    BAR(); MFMAQ(1, 0, blo);
    if (i == NITER - 1) { VMC0(); } else { VMC4(); }
    BAR();
    // ---- K-tile 2i+1 in buf1 ----
    // p5
    RDA(1, 0); RDB(1, 0, blo);
    stageA(0, 0, t2);
    BAR(); MFMAQ(0, 0, blo); BAR();
    // p6
    RDB(1, 1, bhi);
    stageA(0, 1, t2);
    BAR(); MFMAQ(0, 1, bhi); BAR();
    // p7
    RDA(1, 1);
    stageB(1, 0, t3);
    BAR(); MFMAQ(1, 1, bhi); BAR();
    // p8
    stageB(1, 1, t3);
    BAR(); MFMAQ(1, 0, blo);
    if (i < NITER - 1) { VMC4(); }
    BAR();
  }

  // ---- fused epilogue: bias + GroupNorm(32) + SiLU * mw * SiLU ----
  // C/D frag: col = cb + ni*16 + llo ; row = rb + mi*16 + lhi*4 + j
  int cb = col0 + wn * 64;   // 2 groups of 32 per wave
  int rb = row0 + wm * 128;

  float bias_v[4], mw_v[4];
  #pragma unroll
  for (int ni = 0; ni < 4; ++ni) {
    int c = cb + ni * 16 + llo;
    bias_v[ni] = bias[c];
    mw_v[ni] = mw[c];
  }
  #pragma unroll
  for (int mi = 0; mi < 8; ++mi)
    #pragma unroll
    for (int ni = 0; ni < 4; ++ni)
      #pragma unroll
      for (int j = 0; j < 4; ++j)
        acc[mi][ni][j] += bias_v[ni];

  #pragma unroll
  for (int mi = 0; mi < 8; ++mi) {
    #pragma unroll
    for (int gp = 0; gp < 2; ++gp) {
      int g = (cb >> 5) + gp;
      float gw = gnw[g], gb = gnb[g];
      float s[4], ss[4];
      #pragma unroll
      for (int j = 0; j < 4; ++j) {
        float a0 = acc[mi][2 * gp][j];
        float a1 = acc[mi][2 * gp + 1][j];
        s[j] = a0 + a1;
        ss[j] = a0 * a0 + a1 * a1;
      }
      #pragma unroll
      for (int off = 1; off < 16; off <<= 1) {
        #pragma unroll
        for (int j = 0; j < 4; ++j) {
          s[j]  += __shfl_xor(s[j],  off, 64);
          ss[j] += __shfl_xor(ss[j], off, 64);
        }
      }
      #pragma unroll
      for (int j = 0; j < 4; ++j) {
        float mean = s[j] * (1.0f / 32.0f);
        float var  = ss[j] * (1.0f / 32.0f) - mean * mean;
        float rstd = rsqrtf(var + EPSV);
        int r = rb + mi * 16 + lhi * 4 + j;
        #pragma unroll
        for (int nn = 0; nn < 2; ++nn) {
          int ni = 2 * gp + nn;
          float v = (acc[mi][ni][j] - mean) * rstd * gw + gb;
          v = v / (1.0f + __expf(-v));   // SiLU
          v = v * mw_v[ni];
          v = v / (1.0f + __expf(-v));   // SiLU
          out[(size_t)r * NN + (cb + ni * 16 + llo)] = v;
        }
      }
    }
  }
}

// ---------------- naive f32 fallback (only if ws too small) ----------------
__global__ void naive_gemm(const float* __restrict__ x, const float* __restrict__ w,
                           const float* __restrict__ bias, float* __restrict__ out) {
  size_t idx = (size_t)blockIdx.x * 256 + threadIdx.x;
  int m = (int)(idx >> 11);
  int n = (int)(idx & 2047);
  const float* xr = x + (size_t)m * KK;
  const float* wr = w + (size_t)n * KK;
  float s = bias[n];
  for (int k = 0; k < KK; k += 4)
    s += xr[k] * wr[k] + xr[k+1] * wr[k+1] + xr[k+2] * wr[k+2] + xr[k+3] * wr[k+3];
  out[idx] = s;
}

__global__ void naive_post(float* __restrict__ out, const float* __restrict__ gnw,
                           const float* __restrict__ gnb, const float* __restrict__ mw) {
  size_t idx = (size_t)blockIdx.x * 256 + threadIdx.x;  // M*G
  int m = (int)(idx >> 6);
  int g = (int)(idx & 63);
  float* p = out + (size_t)m * NN + g * 32;
  float s = 0.f, ss = 0.f;
  for (int j = 0; j < 32; ++j) { float v = p[j]; s += v; ss += v * v; }
  float mean = s * (1.0f / 32.0f);
  float var  = ss * (1.0f / 32.0f) - mean * mean;
  float rstd = rsqrtf(var + EPSV);
  float gw = gnw[g], gb = gnb[g];
  for (int j = 0; j < 32; ++j) {
    float v = (p[j] - mean) * rstd * gw + gb;
    v = v / (1.0f + __expf(-v));
    v = v * mw[g * 32 + j];
    v = v / (1.0f + __expf(-v));
    p[j] = v;
  }
}

extern "C" void kernel_launch(void* const* d_in, const int* in_sizes, int n_in,
                              void* d_out, int out_size, void* d_ws, size_t ws_size,
                              hipStream_t stream) {
  const float* x    = (const float*)d_in[0];
  const float* wgt  = (const float*)d_in[1];
  const float* bias = (const float*)d_in[2];
  const float* gnw  = (const float*)d_in[3];
  const float* gnb  = (const float*)d_in[4];
  const float* mwp  = (const float*)d_in[5];
  float* out = (float*)d_out;

  size_t need = ((size_t)MM * KK + (size_t)NN * KK) * 2;
  if (ws_size >= need) {
    uint16_t* xbf = (uint16_t*)d_ws;
    uint16_t* wbf = xbf + (size_t)MM * KK;
    cvt_f32_to_bf16<<<2048, 256, 0, stream>>>(x, xbf, (MM * KK) / 4);
    cvt_f32_to_bf16<<<512, 256, 0, stream>>>(wgt, wbf, (NN * KK) / 4);
    (void)hipFuncSetAttribute((const void*)gemm_gn_silu_8p,
                              hipFuncAttributeMaxDynamicSharedMemorySize, 131072);
    gemm_gn_silu_8p<<<512, 512, 131072, stream>>>(xbf, wbf, bias, gnw, gnb, mwp, out);
  } else {
    naive_gemm<<<(MM * (size_t)NN) / 256, 256, 0, stream>>>(x, wgt, bias, out);
    naive_post<<<(MM * GG) / 256, 256, 0, stream>>>(out, gnw, gnb, mwp);
  }
}